// Round 1
// baseline (116.664 us; speedup 1.0000x reference)
//
#include <hip/hip_runtime.h>

// VolumeRenderer R11b (R11 with the nonexistent cvt builtins replaced by
// plain byte-extract casts -- LLVM emits v_cvt_f32_ubyte* for these).
// Theory recap: R10 showed the mask machinery made the render VALU/serial-
// bound (77% VALUBusy) while R9 proved fetch-bytes don't bind -> the
// occupancy mask is pure overhead: dead voxels already have sigma-u8==0, so
// att=exp(-d*0)=1 is an EXACT no-op through the shading math itself.
// R11 = R7 frame (NSEG=4, 4 waves/SIMD) + brick layout (brick-run ~4 steps
// keeps voxel lines L1-hot) + ONE unconditional gather per step, no masks.
// cvt: thread = 4 z-voxels (64B coalesced read, uint4 write, fast sigmoid).

constexpr int   R_DIM    = 128;
constexpr int   N_VOX    = R_DIM * R_DIM * R_DIM;
constexpr int   N_STEPS  = 192;
constexpr int   NSEG     = 4;
constexpr int   SEG_LEN  = N_STEPS / NSEG;   // 48
constexpr float STEP_SZ  = 0.001f;
constexpr float CUBE_SZ  = 1.0f / 128.0f;
constexpr int   PIPE     = 8;
constexpr float SIG_MAX  = 5.5f;

__device__ __forceinline__ float sigmoid_fast(float x) {
    return __builtin_amdgcn_rcpf(1.0f + __expf(-x));
}

__device__ __forceinline__ int clamp_idx(float v) {
    int i = (int)floorf(v);
    i = i < 0 ? 0 : i;
    i = i > (R_DIM - 1) ? (R_DIM - 1) : i;
    return i;
}

// One geometric DDA step -> cell coords + exact delta. Single definition, all
// IEEE __f*_rn (no contraction): prewalk/render t-sequences bit-identical.
// smin==0 exactly (f in [0,1] -> every per-axis lo <= 0).
__device__ __forceinline__ void geom_step(
    float tl, float tmax,
    float ox, float oy, float oz, float dx, float dy, float dz,
    float ix, float iy, float iz,
    int& i0, int& i1, int& i2, float& d)
{
    float px = __fmul_rn(__fadd_rn(ox, __fmul_rn(tl, dx)), (float)R_DIM);
    float py = __fmul_rn(__fadd_rn(oy, __fmul_rn(tl, dy)), (float)R_DIM);
    float pz = __fmul_rn(__fadd_rn(oz, __fmul_rn(tl, dz)), (float)R_DIM);
    i0 = clamp_idx(px);
    i1 = clamp_idx(py);
    i2 = clamp_idx(pz);

    float fx = __fsub_rn(px, (float)i0);
    float fy = __fsub_rn(py, (float)i1);
    float fz = __fsub_rn(pz, (float)i2);

    float t1x = __fmul_rn(-fx, ix), t2x = __fadd_rn(t1x, ix);
    float t1y = __fmul_rn(-fy, iy), t2y = __fadd_rn(t1y, iy);
    float t1z = __fmul_rn(-fz, iz), t2z = __fadd_rn(t1z, iz);
    float hix = fmaxf(t1x, t2x);
    float hiy = fmaxf(t1y, t2y);
    float hiz = fmaxf(t1z, t2z);
    float smax = fminf(fminf(fminf(hix, hiy), hiz), 1e9f);

    d = __fadd_rn(__fmul_rn(smax, CUBE_SZ), STEP_SZ);
    d = (tl < tmax) ? d : 0.0f;   // inactive -> exact no-op (t frozen)
}

__device__ __forceinline__ void ray_setup(
    const float* __restrict__ origins, const float* __restrict__ dirs, int i,
    float& ox, float& oy, float& oz, float& dx, float& dy, float& dz,
    float& ix, float& iy, float& iz, float& tmin, float& tmax)
{
    ox = origins[3 * i + 0];
    oy = origins[3 * i + 1];
    oz = origins[3 * i + 2];
    dx = dirs[3 * i + 0];
    dy = dirs[3 * i + 1];
    dz = dirs[3 * i + 2];

    float n2 = __fadd_rn(__fadd_rn(__fmul_rn(dx, dx), __fmul_rn(dy, dy)),
                         __fmul_rn(dz, dz));
    float nrm = sqrtf(n2);
    dx = dx / nrm;
    dy = dy / nrm;
    dz = dz / nrm;

    ix = 1.0f / __fadd_rn(dx, 1e-9f);
    iy = 1.0f / __fadd_rn(dy, 1e-9f);
    iz = 1.0f / __fadd_rn(dz, 1e-9f);

    float t1x = __fmul_rn(-ox, ix), t2x = __fadd_rn(t1x, ix);
    float t1y = __fmul_rn(-oy, iy), t2y = __fadd_rn(t1y, iy);
    float t1z = __fmul_rn(-oz, iz), t2z = __fadd_rn(t1z, iz);
    float lox = fminf(t1x, t2x), hix = fmaxf(t1x, t2x);
    float loy = fminf(t1y, t2y), hiy = fmaxf(t1y, t2y);
    float loz = fminf(t1z, t2z), hiz = fmaxf(t1z, t2z);
    tmin = fmaxf(fmaxf(fmaxf(lox, loy), loz), 0.0f);
    tmax = fminf(fminf(fminf(hix, hiy), hiz), 1e9f);
}

// ---- pre-pass: fp32 grid -> brick-ordered u8x4 voxels ----------------------
// Thread = 4 consecutive z-voxels (one 64B grid line): 4 coalesced float4
// reads, one uint4 brick-ordered write. 524288 threads, no loop, no ballot.
__device__ __forceinline__ unsigned pack_voxel(float4 v) {
    unsigned ur = (unsigned)__float2int_rn(sigmoid_fast(v.x) * 255.0f);
    unsigned ug = (unsigned)__float2int_rn(sigmoid_fast(v.y) * 255.0f);
    unsigned ub = (unsigned)__float2int_rn(sigmoid_fast(v.z) * 255.0f);
    unsigned us = (unsigned)__float2int_rn(
        fminf(fmaxf(v.w, 0.0f), SIG_MAX) * (255.0f / SIG_MAX));
    return ur | (ug << 8) | (ub << 16) | (us << 24);
}

__global__ __launch_bounds__(256) void cvt_brick(
    const float4* __restrict__ g, uint4* __restrict__ gq4)
{
    int tid = blockIdx.x * blockDim.x + threadIdx.x;
    if (tid >= N_VOX / 4) return;
    int zq = tid & 31;              // z-group (4 voxels)
    int y  = (tid >> 5) & 127;
    int x  = tid >> 12;

    int src = (x * R_DIM + y) * R_DIM + 4 * zq;   // float4 index
    float4 v0 = g[src + 0];
    float4 v1 = g[src + 1];
    float4 v2 = g[src + 2];
    float4 v3 = g[src + 3];

    uint4 o;
    o.x = pack_voxel(v0);
    o.y = pack_voxel(v1);
    o.z = pack_voxel(v2);
    o.w = pack_voxel(v3);

    // brick-ordered destination: bid = bx<<10|by<<5|bz, loc = lx<<4|ly<<2|lz
    int bid = ((x >> 2) << 10) | ((y >> 2) << 5) | zq;
    int dst = bid * 16 + (x & 3) * 4 + (y & 3);     // uint4 index
    gq4[dst] = o;
}

// ---- render: 4 waves/block; wave s renders steps [s*48, s*48+48) -----------
__global__ __launch_bounds__(256) void volrend_seg(
    const unsigned int* __restrict__ gq,   // brick-ordered u8x4, 8.4 MB
    const float* __restrict__ origins,
    const float* __restrict__ dirs,
    float* __restrict__ out,
    int B)
{
    __shared__ float4 lds[64 * (NSEG - 1)];

    int lane = threadIdx.x & 63;
    int seg  = threadIdx.x >> 6;
    int i = blockIdx.x * 64 + lane;

    float ox, oy, oz, dx, dy, dz, ix, iy, iz, tmin, tmax;
    ray_setup(origins, dirs, i, ox, oy, oz, dx, dy, dz, ix, iy, iz, tmin, tmax);

    float t = tmin;

    // --- prewalk: seg*48 geometry-only steps (bit-exact, no loads) ---------
    int pre_chunks = seg * (SEG_LEN / PIPE);
    for (int c = 0; c < pre_chunks; ++c) {
        if (t >= tmax) break;
        #pragma unroll
        for (int p = 0; p < PIPE; ++p) {
            int i0, i1, i2; float d;
            geom_step(t, tmax, ox, oy, oz, dx, dy, dz, ix, iy, iz,
                      i0, i1, i2, d);
            t = __fadd_rn(t, d);
        }
    }

    // --- render 48 steps with local transmittance --------------------------
    float light = 1.0f;
    float ar = 0.0f, ag = 0.0f, ab = 0.0f;

    for (int chunk = 0; chunk < SEG_LEN / PIPE; ++chunk) {
        if (t >= tmax) break;

        unsigned int val[PIPE];
        float del[PIPE];
        float tl = t;

        #pragma unroll
        for (int p = 0; p < PIPE; ++p) {
            int i0, i1, i2; float d;
            geom_step(tl, tmax, ox, oy, oz, dx, dy, dz, ix, iy, iz,
                      i0, i1, i2, d);
            unsigned bid = ((unsigned)(i0 >> 2) << 10) |
                           ((unsigned)(i1 >> 2) << 5) |
                           (unsigned)(i2 >> 2);
            unsigned loc = ((unsigned)(i0 & 3) << 4) |
                           ((unsigned)(i1 & 3) << 2) |
                           (unsigned)(i2 & 3);
            val[p] = gq[(bid << 6) | loc];   // dead voxel: sigma-u8==0 -> att=1
            del[p] = d;
            tl = __fadd_rn(tl, d);
        }

        #pragma unroll
        for (int p = 0; p < PIPE; ++p) {
            unsigned int v = val[p];
            // byte-extract casts compile to v_cvt_f32_ubyte0..3
            float r  = (float)(v & 255u)         * (1.0f / 255.0f);
            float gg = (float)((v >> 8) & 255u)  * (1.0f / 255.0f);
            float b  = (float)((v >> 16) & 255u) * (1.0f / 255.0f);
            float sg = (float)(v >> 24)          * (SIG_MAX / 255.0f);
            float att = __expf(-del[p] * sg);
            float w = light * (1.0f - att);
            ar = fmaf(w, r, ar);
            ag = fmaf(w, gg, ag);
            ab = fmaf(w, b, ab);
            light *= att;
        }

        t = tl;
    }

    // --- compose: out = A0 + L0*(A1 + L1*(A2 + L2*(A3 + L3))) --------------
    if (seg > 0) {
        lds[(seg - 1) * 64 + lane] = make_float4(ar, ag, ab, light);
    }
    __syncthreads();
    if (seg == 0) {
        float4 s1 = lds[0 * 64 + lane];
        float4 s2 = lds[1 * 64 + lane];
        float4 s3 = lds[2 * 64 + lane];
        float r3 = s3.x + s3.w, g3 = s3.y + s3.w, b3 = s3.z + s3.w;
        float r2 = fmaf(s2.w, r3, s2.x);
        float g2 = fmaf(s2.w, g3, s2.y);
        float b2 = fmaf(s2.w, b3, s2.z);
        float r1 = fmaf(s1.w, r2, s1.x);
        float g1 = fmaf(s1.w, g2, s1.y);
        float b1 = fmaf(s1.w, b2, s1.z);
        out[3 * i + 0] = fmaf(light, r1, ar);
        out[3 * i + 1] = fmaf(light, g1, ag);
        out[3 * i + 2] = fmaf(light, b1, ab);
    }
}

// ---- fallback: render straight from fp32 grid (if ws too small) ------------
__global__ __launch_bounds__(256) void volrend_f32(
    const float* __restrict__ grid,
    const float* __restrict__ origins,
    const float* __restrict__ dirs,
    float* __restrict__ out,
    int B)
{
    int i = blockIdx.x * blockDim.x + threadIdx.x;
    if (i >= B) return;

    float ox, oy, oz, dx, dy, dz, ix, iy, iz, tmin, tmax;
    ray_setup(origins, dirs, i, ox, oy, oz, dx, dy, dz, ix, iy, iz, tmin, tmax);

    const float4* __restrict__ g4 = (const float4*)grid;

    float t = tmin;
    float light = 1.0f;
    float ar = 0.0f, ag = 0.0f, ab = 0.0f;

    for (int chunk = 0; chunk < N_STEPS / PIPE; ++chunk) {
        if (t >= tmax) break;

        float4 val[PIPE];
        float del[PIPE];
        float tl = t;

        #pragma unroll
        for (int p = 0; p < PIPE; ++p) {
            int i0, i1, i2; float d;
            geom_step(tl, tmax, ox, oy, oz, dx, dy, dz, ix, iy, iz,
                      i0, i1, i2, d);
            val[p] = g4[(i0 * R_DIM + i1) * R_DIM + i2];
            del[p] = d;
            tl = __fadd_rn(tl, d);
        }

        #pragma unroll
        for (int p = 0; p < PIPE; ++p) {
            float sigma = fmaxf(val[p].w, 0.0f);
            float att = __expf(-del[p] * sigma);
            float w = light * (1.0f - att);
            ar = fmaf(w, sigmoid_fast(val[p].x), ar);
            ag = fmaf(w, sigmoid_fast(val[p].y), ag);
            ab = fmaf(w, sigmoid_fast(val[p].z), ab);
            light *= att;
        }

        t = tl;
    }

    out[3 * i + 0] = ar + light;
    out[3 * i + 1] = ag + light;
    out[3 * i + 2] = ab + light;
}

extern "C" void kernel_launch(void* const* d_in, const int* in_sizes, int n_in,
                              void* d_out, int out_size, void* d_ws, size_t ws_size,
                              hipStream_t stream) {
    const float* grid    = (const float*)d_in[0];
    const float* origins = (const float*)d_in[1];
    const float* dirs    = (const float*)d_in[2];
    float* out = (float*)d_out;

    int B = in_sizes[1] / 3;

    size_t need = (size_t)N_VOX * 4;   // brick-ordered u8x4 voxels, 8.4 MB
    if (ws_size >= need && (B % 64) == 0) {
        uint4* gq4 = (uint4*)d_ws;
        cvt_brick<<<(N_VOX / 4 + 255) / 256, 256, 0, stream>>>(
            (const float4*)grid, gq4);
        volrend_seg<<<B / 64, 64 * NSEG, 0, stream>>>(
            (const unsigned int*)gq4, origins, dirs, out, B);
    } else {
        volrend_f32<<<(B + 255) / 256, 256, 0, stream>>>(grid, origins, dirs,
                                                         out, B);
    }
}

// Round 2
// 107.994 us; speedup vs baseline: 1.0803x; 1.0803x over previous
//
#include <hip/hip_runtime.h>

// VolumeRenderer R12: R11b + bit-exact VALU diet in geom_step.
// Theory: volrend_seg is VALU-issue-bound (77% VALUBusy, HBM far from peak,
// 8.4MB brick grid L2-resident). Cut ops/step with transforms PROVEN
// bit-identical to the reference t-walk:
//  (1) pre-scale origin/dir by R=128 (exact *2^7; scaling lemma:
//      rn(rn(x)*2^7)=rn(x*2^7)) -> px = oxR + tl*dxR, saves 3 muls/step.
//  (2) hi = max(t1, t1+i) == rn(t1 + max(i,0)) for ALL t1 (i>0: rounding
//      monotone; i<=0: +0 identity). ipos precomputed/ray: -3 vmax/step.
//  (3) clamp in float domain: floor -> med3_f32(.,0,127) -> single cvt for
//      the index; fx via (c - px) = -fx exactly (negation sign-symmetric).
//      Removes int-clamp + cvt-back; prewalk drops ALL index cvts (DCE).
//  (4) shading: fold 1/255 into weight (reassoc ~1e-7 << 0.0039 quant floor).
// Frame unchanged: NSEG=4, PIPE=8, brick u8x4 layout, one unconditional
// gather/step (dead voxel sigma-u8==0 -> att=1 exact no-op).

constexpr int   R_DIM    = 128;
constexpr int   N_VOX    = R_DIM * R_DIM * R_DIM;
constexpr int   N_STEPS  = 192;
constexpr int   NSEG     = 4;
constexpr int   SEG_LEN  = N_STEPS / NSEG;   // 48
constexpr float STEP_SZ  = 0.001f;
constexpr float CUBE_SZ  = 1.0f / 128.0f;
constexpr int   PIPE     = 8;
constexpr float SIG_MAX  = 5.5f;

__device__ __forceinline__ float sigmoid_fast(float x) {
    return __builtin_amdgcn_rcpf(1.0f + __expf(-x));
}

// One geometric DDA step -> cell coords + exact delta. Bit-identical to the
// reference walk (see header). smin==0 exactly (f in [0,1] -> every lo <= 0).
__device__ __forceinline__ void geom_step(
    float tl, float tmax,
    float oxR, float oyR, float ozR, float dxR, float dyR, float dzR,
    float ix, float iy, float iz, float ipx, float ipy, float ipz,
    int& i0, int& i1, int& i2, float& d)
{
    float px = __fadd_rn(oxR, __fmul_rn(tl, dxR));
    float py = __fadd_rn(oyR, __fmul_rn(tl, dyR));
    float pz = __fadd_rn(ozR, __fmul_rn(tl, dzR));

    // float-domain clamp: med3(floor(p), 0, 127); same value as int clamp
    float c0 = fminf(fmaxf(floorf(px), 0.0f), 127.0f);
    float c1 = fminf(fmaxf(floorf(py), 0.0f), 127.0f);
    float c2 = fminf(fmaxf(floorf(pz), 0.0f), 127.0f);
    i0 = (int)c0;   // dead (DCE'd) in prewalk
    i1 = (int)c1;
    i2 = (int)c2;

    // t1 = rn((-f)*i) via (c-p) = -f exactly; hi = rn(t1 + max(i,0))
    float t1x = __fmul_rn(__fsub_rn(c0, px), ix);
    float t1y = __fmul_rn(__fsub_rn(c1, py), iy);
    float t1z = __fmul_rn(__fsub_rn(c2, pz), iz);
    float hix = __fadd_rn(t1x, ipx);
    float hiy = __fadd_rn(t1y, ipy);
    float hiz = __fadd_rn(t1z, ipz);
    float smax = fminf(fminf(fminf(hix, hiy), hiz), 1e9f);

    d = __fadd_rn(__fmul_rn(smax, CUBE_SZ), STEP_SZ);
    d = (tl < tmax) ? d : 0.0f;   // inactive -> exact no-op (t frozen)
}

__device__ __forceinline__ void ray_setup(
    const float* __restrict__ origins, const float* __restrict__ dirs, int i,
    float& oxR, float& oyR, float& ozR, float& dxR, float& dyR, float& dzR,
    float& ix, float& iy, float& iz,
    float& ipx, float& ipy, float& ipz,
    float& tmin, float& tmax)
{
    float ox = origins[3 * i + 0];
    float oy = origins[3 * i + 1];
    float oz = origins[3 * i + 2];
    float dx = dirs[3 * i + 0];
    float dy = dirs[3 * i + 1];
    float dz = dirs[3 * i + 2];

    float n2 = __fadd_rn(__fadd_rn(__fmul_rn(dx, dx), __fmul_rn(dy, dy)),
                         __fmul_rn(dz, dz));
    float nrm = sqrtf(n2);
    dx = dx / nrm;
    dy = dy / nrm;
    dz = dz / nrm;

    ix = 1.0f / __fadd_rn(dx, 1e-9f);
    iy = 1.0f / __fadd_rn(dy, 1e-9f);
    iz = 1.0f / __fadd_rn(dz, 1e-9f);

    ipx = fmaxf(ix, 0.0f);
    ipy = fmaxf(iy, 0.0f);
    ipz = fmaxf(iz, 0.0f);

    float t1x = __fmul_rn(-ox, ix), t2x = __fadd_rn(t1x, ix);
    float t1y = __fmul_rn(-oy, iy), t2y = __fadd_rn(t1y, iy);
    float t1z = __fmul_rn(-oz, iz), t2z = __fadd_rn(t1z, iz);
    float lox = fminf(t1x, t2x), hix = fmaxf(t1x, t2x);
    float loy = fminf(t1y, t2y), hiy = fmaxf(t1y, t2y);
    float loz = fminf(t1z, t2z), hiz = fmaxf(t1z, t2z);
    tmin = fmaxf(fmaxf(fmaxf(lox, loy), loz), 0.0f);
    tmax = fminf(fminf(fminf(hix, hiy), hiz), 1e9f);

    // exact *2^7 (scaling lemma keeps the walk bit-identical)
    oxR = __fmul_rn(ox, 128.0f);
    oyR = __fmul_rn(oy, 128.0f);
    ozR = __fmul_rn(oz, 128.0f);
    dxR = __fmul_rn(dx, 128.0f);
    dyR = __fmul_rn(dy, 128.0f);
    dzR = __fmul_rn(dz, 128.0f);
}

// ---- pre-pass: fp32 grid -> brick-ordered u8x4 voxels ----------------------
// Thread = 4 consecutive z-voxels (one 64B grid line): 4 coalesced float4
// reads, one uint4 brick-ordered write. 524288 threads, no loop, no ballot.
__device__ __forceinline__ unsigned pack_voxel(float4 v) {
    unsigned ur = (unsigned)__float2int_rn(sigmoid_fast(v.x) * 255.0f);
    unsigned ug = (unsigned)__float2int_rn(sigmoid_fast(v.y) * 255.0f);
    unsigned ub = (unsigned)__float2int_rn(sigmoid_fast(v.z) * 255.0f);
    unsigned us = (unsigned)__float2int_rn(
        fminf(fmaxf(v.w, 0.0f), SIG_MAX) * (255.0f / SIG_MAX));
    return ur | (ug << 8) | (ub << 16) | (us << 24);
}

__global__ __launch_bounds__(256) void cvt_brick(
    const float4* __restrict__ g, uint4* __restrict__ gq4)
{
    int tid = blockIdx.x * blockDim.x + threadIdx.x;
    if (tid >= N_VOX / 4) return;
    int zq = tid & 31;              // z-group (4 voxels)
    int y  = (tid >> 5) & 127;
    int x  = tid >> 12;

    int src = (x * R_DIM + y) * R_DIM + 4 * zq;   // float4 index
    float4 v0 = g[src + 0];
    float4 v1 = g[src + 1];
    float4 v2 = g[src + 2];
    float4 v3 = g[src + 3];

    uint4 o;
    o.x = pack_voxel(v0);
    o.y = pack_voxel(v1);
    o.z = pack_voxel(v2);
    o.w = pack_voxel(v3);

    // brick-ordered destination: bid = bx<<10|by<<5|bz, loc = lx<<4|ly<<2|lz
    int bid = ((x >> 2) << 10) | ((y >> 2) << 5) | zq;
    int dst = bid * 16 + (x & 3) * 4 + (y & 3);     // uint4 index
    gq4[dst] = o;
}

// ---- render: 4 waves/block; wave s renders steps [s*48, s*48+48) -----------
__global__ __launch_bounds__(256) void volrend_seg(
    const unsigned int* __restrict__ gq,   // brick-ordered u8x4, 8.4 MB
    const float* __restrict__ origins,
    const float* __restrict__ dirs,
    float* __restrict__ out,
    int B)
{
    __shared__ float4 lds[64 * (NSEG - 1)];

    int lane = threadIdx.x & 63;
    int seg  = threadIdx.x >> 6;
    int i = blockIdx.x * 64 + lane;

    float oxR, oyR, ozR, dxR, dyR, dzR, ix, iy, iz, ipx, ipy, ipz, tmin, tmax;
    ray_setup(origins, dirs, i, oxR, oyR, ozR, dxR, dyR, dzR,
              ix, iy, iz, ipx, ipy, ipz, tmin, tmax);

    float t = tmin;

    // --- prewalk: seg*48 geometry-only steps (bit-exact, no loads) ---------
    int pre_chunks = seg * (SEG_LEN / PIPE);
    for (int c = 0; c < pre_chunks; ++c) {
        if (t >= tmax) break;
        #pragma unroll
        for (int p = 0; p < PIPE; ++p) {
            int i0, i1, i2; float d;
            geom_step(t, tmax, oxR, oyR, ozR, dxR, dyR, dzR,
                      ix, iy, iz, ipx, ipy, ipz, i0, i1, i2, d);
            t = __fadd_rn(t, d);
        }
    }

    // --- render 48 steps with local transmittance --------------------------
    float light = 1.0f;
    float ar = 0.0f, ag = 0.0f, ab = 0.0f;

    for (int chunk = 0; chunk < SEG_LEN / PIPE; ++chunk) {
        if (t >= tmax) break;

        unsigned int val[PIPE];
        float del[PIPE];
        float tl = t;

        #pragma unroll
        for (int p = 0; p < PIPE; ++p) {
            int i0, i1, i2; float d;
            geom_step(tl, tmax, oxR, oyR, ozR, dxR, dyR, dzR,
                      ix, iy, iz, ipx, ipy, ipz, i0, i1, i2, d);
            unsigned bid = ((unsigned)(i0 >> 2) << 10) |
                           ((unsigned)(i1 >> 2) << 5) |
                           (unsigned)(i2 >> 2);
            unsigned loc = ((unsigned)(i0 & 3) << 4) |
                           ((unsigned)(i1 & 3) << 2) |
                           (unsigned)(i2 & 3);
            val[p] = gq[(bid << 6) | loc];   // dead voxel: sigma-u8==0 -> att=1
            del[p] = d;
            tl = __fadd_rn(tl, d);
        }

        #pragma unroll
        for (int p = 0; p < PIPE; ++p) {
            unsigned int v = val[p];
            // byte-extract casts compile to v_cvt_f32_ubyte0..3
            float r  = (float)(v & 255u);
            float gg = (float)((v >> 8) & 255u);
            float b  = (float)((v >> 16) & 255u);
            float sg = (float)(v >> 24);
            float att = __expf(del[p] * (-SIG_MAX / 255.0f) * sg);
            float w  = light * (1.0f - att);
            float ws = w * (1.0f / 255.0f);
            ar = fmaf(ws, r, ar);
            ag = fmaf(ws, gg, ag);
            ab = fmaf(ws, b, ab);
            light *= att;
        }

        t = tl;
    }

    // --- compose: out = A0 + L0*(A1 + L1*(A2 + L2*(A3 + L3))) --------------
    if (seg > 0) {
        lds[(seg - 1) * 64 + lane] = make_float4(ar, ag, ab, light);
    }
    __syncthreads();
    if (seg == 0) {
        float4 s1 = lds[0 * 64 + lane];
        float4 s2 = lds[1 * 64 + lane];
        float4 s3 = lds[2 * 64 + lane];
        float r3 = s3.x + s3.w, g3 = s3.y + s3.w, b3 = s3.z + s3.w;
        float r2 = fmaf(s2.w, r3, s2.x);
        float g2 = fmaf(s2.w, g3, s2.y);
        float b2 = fmaf(s2.w, b3, s2.z);
        float r1 = fmaf(s1.w, r2, s1.x);
        float g1 = fmaf(s1.w, g2, s1.y);
        float b1 = fmaf(s1.w, b2, s1.z);
        out[3 * i + 0] = fmaf(light, r1, ar);
        out[3 * i + 1] = fmaf(light, g1, ag);
        out[3 * i + 2] = fmaf(light, b1, ab);
    }
}

// ---- fallback: render straight from fp32 grid (if ws too small) ------------
__global__ __launch_bounds__(256) void volrend_f32(
    const float* __restrict__ grid,
    const float* __restrict__ origins,
    const float* __restrict__ dirs,
    float* __restrict__ out,
    int B)
{
    int i = blockIdx.x * blockDim.x + threadIdx.x;
    if (i >= B) return;

    float oxR, oyR, ozR, dxR, dyR, dzR, ix, iy, iz, ipx, ipy, ipz, tmin, tmax;
    ray_setup(origins, dirs, i, oxR, oyR, ozR, dxR, dyR, dzR,
              ix, iy, iz, ipx, ipy, ipz, tmin, tmax);

    const float4* __restrict__ g4 = (const float4*)grid;

    float t = tmin;
    float light = 1.0f;
    float ar = 0.0f, ag = 0.0f, ab = 0.0f;

    for (int chunk = 0; chunk < N_STEPS / PIPE; ++chunk) {
        if (t >= tmax) break;

        float4 val[PIPE];
        float del[PIPE];
        float tl = t;

        #pragma unroll
        for (int p = 0; p < PIPE; ++p) {
            int i0, i1, i2; float d;
            geom_step(tl, tmax, oxR, oyR, ozR, dxR, dyR, dzR,
                      ix, iy, iz, ipx, ipy, ipz, i0, i1, i2, d);
            val[p] = g4[(i0 * R_DIM + i1) * R_DIM + i2];
            del[p] = d;
            tl = __fadd_rn(tl, d);
        }

        #pragma unroll
        for (int p = 0; p < PIPE; ++p) {
            float sigma = fmaxf(val[p].w, 0.0f);
            float att = __expf(-del[p] * sigma);
            float w = light * (1.0f - att);
            ar = fmaf(w, sigmoid_fast(val[p].x), ar);
            ag = fmaf(w, sigmoid_fast(val[p].y), ag);
            ab = fmaf(w, sigmoid_fast(val[p].z), ab);
            light *= att;
        }

        t = tl;
    }

    out[3 * i + 0] = ar + light;
    out[3 * i + 1] = ag + light;
    out[3 * i + 2] = ab + light;
}

extern "C" void kernel_launch(void* const* d_in, const int* in_sizes, int n_in,
                              void* d_out, int out_size, void* d_ws, size_t ws_size,
                              hipStream_t stream) {
    const float* grid    = (const float*)d_in[0];
    const float* origins = (const float*)d_in[1];
    const float* dirs    = (const float*)d_in[2];
    float* out = (float*)d_out;

    int B = in_sizes[1] / 3;

    size_t need = (size_t)N_VOX * 4;   // brick-ordered u8x4 voxels, 8.4 MB
    if (ws_size >= need && (B % 64) == 0) {
        uint4* gq4 = (uint4*)d_ws;
        cvt_brick<<<(N_VOX / 4 + 255) / 256, 256, 0, stream>>>(
            (const float4*)grid, gq4);
        volrend_seg<<<B / 64, 64 * NSEG, 0, stream>>>(
            (const unsigned int*)gq4, origins, dirs, out, B);
    } else {
        volrend_f32<<<(B + 255) / 256, 256, 0, stream>>>(grid, origins, dirs,
                                                         out, B);
    }
}